// Round 1
// 326.517 us; speedup vs baseline: 1.0192x; 1.0192x over previous
//
#include <hip/hip_runtime.h>

// RSCA fused + software-pipelined. Blocks own G=4 groups of TC=4 columns.
// Pool loads for group g+1 are issued before attention(g) and reduced after
// it, so HBM streaming hides under the exp2-bound attention issue stream.
// LDS holds only RAW values (k-affine folded into per-query constants:
// score*log2e = v*(q*wkL) + (q*bkL + nm)); inner loop per jj-pair per combo
// is 1 v_pk_fma + 2 v_exp + 1 v_pk_fma + 1 v_pk_add via ext_vector float2.
// Min/max via wave shuffle butterfly (removes the 32-way-conflict phase).
// Output staged in padded LDS obuf, flushed as aligned row float4s.

constexpr int B_SEQ = 128;
constexpr int N_COL = 8192;
constexpr int HWP   = 49;
constexpr int NT    = 256;
constexpr int TC    = 4;      // columns per group
constexpr int G     = 4;      // groups per block (pipeline depth)
constexpr int CPB   = TC * G; // 16 columns per block
constexpr int VSTR  = 132;    // padded LDS row stride (floats): conflict-free writes, 16B-aligned rows
constexpr int OSTR  = 21;     // obuf row stride: gcd(21,32)=1 -> conflict-free scatter writes

typedef float v2f __attribute__((ext_vector_type(2)));

#if __has_builtin(__builtin_elementwise_fma)
#define VFMA(a, b, c) __builtin_elementwise_fma((a), (b), (c))
#else
__device__ __forceinline__ v2f VFMA(v2f a, v2f b, v2f c) {
    v2f r; r.x = fmaf(a.x, b.x, c.x); r.y = fmaf(a.y, b.y, c.y); return r;
}
#endif

__global__ __launch_bounds__(NT, 2) void rsca_fused(
    const float* __restrict__ x, const float* __restrict__ y,
    const float* __restrict__ pwq, const float* __restrict__ pwk,
    const float* __restrict__ pwv, const float* __restrict__ pbq,
    const float* __restrict__ pbk, const float* __restrict__ pbv,
    const float* __restrict__ pwo, const float* __restrict__ pbo,
    float* __restrict__ out)
{
    __shared__ float vls[2][2][TC * VSTR];  // [buf][set x/y][c*VSTR + j] raw values
    __shared__ float pmn[2][2][8][TC];      // [buf][set][slot][c] wave partial min (raw)
    __shared__ float pmx[2][2][8][TC];
    __shared__ float obuf[2][B_SEQ * OSTR]; // [set][i*OSTR + blockcol]

    const int t       = threadIdx.x;
    const int bid     = blockIdx.x;
    const int colbase = bid * CPB;
    const int ql      = t & 3;   // column-in-group lane
    const int seg     = t >> 2;  // 0..63 -> row
    const int lane    = t & 63;
    const int wid     = t >> 6;

    const float wq = pwq[0], wk = pwk[0], wv = pwv[0];
    const float bq = pbq[0], bk = pbk[0], bv = pbv[0];
    const float wo = pwo[0], bo = pbo[0];
    const float L2E = 1.4426950408889634f;
    const float wkL = wk * L2E, bkL = bk * L2E;
    const float alpha = wo * wv;
    const float beta2 = 2.0f * (wo * bv + bo);

    auto issue_pass = [&](int g, int p, float4 (&v)[13]) {
        const int j = p * 64 + seg;
        const float4* __restrict__ base =
            (const float4*)(x + ((size_t)j * N_COL + colbase + g * TC) * (size_t)HWP);
        #pragma unroll
        for (int k = 0; k < 12; ++k) v[k] = base[ql + 4 * k];
        v[12] = base[48];
    };

    auto reduce_pass = [&](int p, int nb, const float4 (&v)[13]) {
        float s0 = 0.f, s1 = 0.f, s2 = 0.f, s3 = 0.f;
        s0 += v[0].x + v[0].y + v[0].z + v[0].w;
        s0 += v[1].x + v[1].y + v[1].z + v[1].w;
        s0 += v[2].x + v[2].y + v[2].z + v[2].w;
        s1 += v[4].x + v[4].y + v[4].z + v[4].w;
        s1 += v[5].x + v[5].y + v[5].z + v[5].w;
        s2 += v[7].x + v[7].y + v[7].z + v[7].w;
        s2 += v[8].x + v[8].y + v[8].z + v[8].w;
        s3 += v[10].x + v[10].y + v[10].z + v[10].w;
        s3 += v[11].x + v[11].y + v[11].z + v[11].w;
        { const float sm = v[3].x + v[3].y + v[3].z + v[3].w;
          const float cr = (ql == 0) ? v[3].x : 0.0f;
          s0 += cr; s1 += sm - cr; }
        { const float sm = v[6].x + v[6].y + v[6].z + v[6].w;
          const float cr = (ql == 0) ? (v[6].x + v[6].y) : 0.0f;
          s1 += cr; s2 += sm - cr; }
        { const float sm = v[9].x + v[9].y + v[9].z + v[9].w;
          const float cr = (ql == 0) ? (v[9].x + v[9].y + v[9].z) : 0.0f;
          s2 += cr; s3 += sm - cr; }
        const float tail = v[12].x + v[12].y + v[12].z + v[12].w;
        s0 += __shfl_xor(s0, 1); s1 += __shfl_xor(s1, 1);
        s2 += __shfl_xor(s2, 1); s3 += __shfl_xor(s3, 1);
        s0 += __shfl_xor(s0, 2); s1 += __shfl_xor(s1, 2);
        s2 += __shfl_xor(s2, 2); s3 += __shfl_xor(s3, 2);
        float r = s0;
        r = (ql == 1) ? s1 : r;
        r = (ql == 2) ? s2 : r;
        r = (ql == 3) ? (s3 + tail) : r;
        const float mean = r * (1.0f / HWP);
        const int j = p * 64 + seg;
        vls[nb][0][ql * VSTR + j] = mean;
        // wave min/max over the 16 rows this wave produced (same ql lanes)
        float mn = mean, mx = mean;
        #pragma unroll
        for (int off = 4; off <= 32; off <<= 1) {
            mn = fminf(mn, __shfl_xor(mn, off));
            mx = fmaxf(mx, __shfl_xor(mx, off));
        }
        if (lane < 4) {
            pmn[nb][0][p * 4 + wid][ql] = mn;
            pmx[nb][0][p * 4 + wid][ql] = mx;
        }
    };

    auto stage_y = [&](int nb, float fy0, float fy1) {
        vls[nb][1][ql * VSTR + seg]      = fy0;
        vls[nb][1][ql * VSTR + seg + 64] = fy1;
        float mn = fminf(fy0, fy1), mx = fmaxf(fy0, fy1);
        #pragma unroll
        for (int off = 4; off <= 32; off <<= 1) {
            mn = fminf(mn, __shfl_xor(mn, off));
            mx = fmaxf(mx, __shfl_xor(mx, off));
        }
        if (lane < 4) {
            pmn[nb][1][wid][ql] = mn;
            pmx[nb][1][wid][ql] = mx;
        }
    };

    const int ch = t >> 7;
    const int i  = t & (B_SEQ - 1);

    auto attn = [&](int g, int cb, int cc) {
        const int c = ch * 2 + cc;                     // wave-uniform -> LDS broadcast
        const float* __restrict__ vx = &vls[cb][0][c * VSTR];
        const float* __restrict__ vy = &vls[cb][1][c * VSTR];

        // fold partials -> raw min/max -> k-domain bounds (wkL sign handled by fmax/fmin)
        float vxmn = pmn[cb][0][0][c], vxmx = pmx[cb][0][0][c];
        #pragma unroll
        for (int s = 1; s < 8; ++s) {
            vxmn = fminf(vxmn, pmn[cb][0][s][c]);
            vxmx = fmaxf(vxmx, pmx[cb][0][s][c]);
        }
        float vymn = pmn[cb][1][0][c], vymx = pmx[cb][1][0][c];
        #pragma unroll
        for (int s = 1; s < 4; ++s) {
            vymn = fminf(vymn, pmn[cb][1][s][c]);
            vymx = fmaxf(vymx, pmx[cb][1][s][c]);
        }
        const float axv = fmaf(vxmx, wkL, bkL), bxv = fmaf(vxmn, wkL, bkL);
        const float kxmx = fmaxf(axv, bxv), kxmn = fminf(axv, bxv);
        const float ayv = fmaf(vymx, wkL, bkL), byv = fmaf(vymn, wkL, bkL);
        const float kymx = fmaxf(ayv, byv), kymn = fminf(ayv, byv);

        const float xi = vx[i], yi = vy[i];
        const float qx = fmaf(xi, wq, bq), qy = fmaf(yi, wq, bq);
        const float nmsx = -(qx >= 0.f ? qx * kxmx : qx * kxmn);
        const float nmcy = -(qy >= 0.f ? qy * kxmx : qy * kxmn);
        const float nmsy = -(qy >= 0.f ? qy * kymx : qy * kymn);
        const float nmcx = -(qx >= 0.f ? qx * kymx : qx * kymn);

        // score*log2e = v*(q*wkL) + (q*bkL + nm)
        const float qxw = qx * wkL, qyw = qy * wkL;
        const v2f qxw2 = {qxw, qxw}, qyw2 = {qyw, qyw};
        const float csx = fmaf(qx, bkL, nmsx), ccy = fmaf(qy, bkL, nmcy);
        const float csy = fmaf(qy, bkL, nmsy), ccx = fmaf(qx, bkL, nmcx);
        const v2f csx2 = {csx, csx}, ccy2 = {ccy, ccy};
        const v2f csy2 = {csy, csy}, ccx2 = {ccx, ccx};

        v2f s0sx = {0.f, 0.f}, s1sx = {0.f, 0.f};
        v2f s0cy = {0.f, 0.f}, s1cy = {0.f, 0.f};
        v2f s0sy = {0.f, 0.f}, s1sy = {0.f, 0.f};
        v2f s0cx = {0.f, 0.f}, s1cx = {0.f, 0.f};

        for (int j0 = 0; j0 < B_SEQ; j0 += 8) {
            const float4 a0 = *(const float4*)&vx[j0];
            const float4 a1 = *(const float4*)&vx[j0 + 4];
            const float4 b0 = *(const float4*)&vy[j0];
            const float4 b1 = *(const float4*)&vy[j0 + 4];
            auto px2 = [&](float v0, float v1) {
                const v2f vv = {v0, v1};
                v2f t1 = VFMA(qxw2, vv, csx2);
                v2f e1; e1.x = __builtin_amdgcn_exp2f(t1.x);
                        e1.y = __builtin_amdgcn_exp2f(t1.y);
                s1sx = VFMA(e1, vv, s1sx); s0sx += e1;
                v2f t2 = VFMA(qyw2, vv, ccy2);
                v2f e2; e2.x = __builtin_amdgcn_exp2f(t2.x);
                        e2.y = __builtin_amdgcn_exp2f(t2.y);
                s1cy = VFMA(e2, vv, s1cy); s0cy += e2;
            };
            auto py2 = [&](float v0, float v1) {
                const v2f vv = {v0, v1};
                v2f t3 = VFMA(qyw2, vv, csy2);
                v2f e3; e3.x = __builtin_amdgcn_exp2f(t3.x);
                        e3.y = __builtin_amdgcn_exp2f(t3.y);
                s1sy = VFMA(e3, vv, s1sy); s0sy += e3;
                v2f t4 = VFMA(qxw2, vv, ccx2);
                v2f e4; e4.x = __builtin_amdgcn_exp2f(t4.x);
                        e4.y = __builtin_amdgcn_exp2f(t4.y);
                s1cx = VFMA(e4, vv, s1cx); s0cx += e4;
            };
            px2(a0.x, a0.y); px2(a0.z, a0.w); px2(a1.x, a1.y); px2(a1.z, a1.w);
            py2(b0.x, b0.y); py2(b0.z, b0.w); py2(b1.x, b1.y); py2(b1.z, b1.w);
        }
        const float S0sx = s0sx.x + s0sx.y, S1sx = s1sx.x + s1sx.y;
        const float S0cy = s0cy.x + s0cy.y, S1cy = s1cy.x + s1cy.y;
        const float S0sy = s0sy.x + s0sy.y, S1sy = s1sy.x + s1sy.y;
        const float S0cx = s0cx.x + s0cx.y, S1cx = s1cx.x + s1cx.y;
        const float mx_attn = S1sx * __builtin_amdgcn_rcpf(S0sx)
                            + S1cx * __builtin_amdgcn_rcpf(S0cx);
        const float my_attn = S1sy * __builtin_amdgcn_rcpf(S0sy)
                            + S1cy * __builtin_amdgcn_rcpf(S0cy);
        obuf[0][i * OSTR + g * TC + c] = fmaf(alpha, mx_attn, beta2 + xi);
        obuf[1][i * OSTR + g * TC + c] = fmaf(alpha, my_attn, beta2 + yi);
    };

    // ---- prologue: fill buffer 0 for group 0 (exposed pipeline fill) ----
    float4 va[13], vb[13];
    float fy0, fy1;
    {
        const int col = colbase + ql;
        issue_pass(0, 0, va);
        issue_pass(0, 1, vb);
        fy0 = y[(size_t)seg * N_COL + col];
        fy1 = y[(size_t)(seg + 64) * N_COL + col];
        reduce_pass(0, 0, va);
        stage_y(0, fy0, fy1);
        reduce_pass(1, 0, vb);
    }
    __syncthreads();

    // ---- pipelined main loop: attn(g) over buf cur, pool(g+1) into buf cur^1 ----
    int cur = 0;
    for (int g = 0; g < G; ++g) {
        const int nb = cur ^ 1;
        const bool pf = (g + 1 < G);
        if (pf) {
            const int col = colbase + (g + 1) * TC + ql;
            issue_pass(g + 1, 0, va);               // loads in flight across attn cc=0
            fy0 = y[(size_t)seg * N_COL + col];
            fy1 = y[(size_t)(seg + 64) * N_COL + col];
        }
        attn(g, cur, 0);
        if (pf) {
            reduce_pass(0, nb, va);
            stage_y(nb, fy0, fy1);
            issue_pass(g + 1, 1, vb);               // loads in flight across attn cc=1
        }
        attn(g, cur, 1);
        if (pf) reduce_pass(1, nb, vb);
        __syncthreads();
        cur = nb;
    }

    // ---- coalesced flush: 64B row segments, aligned (colbase*4 % 64 == 0) ----
    #pragma unroll
    for (int idx = t; idx < 2 * B_SEQ * TC; idx += NT) {
        const int set = idx >> 9;
        const int rem = idx & 511;
        const int ii  = rem >> 2;
        const int q   = rem & 3;
        const float* p = &obuf[set][ii * OSTR + q * 4];
        float4 val;
        val.x = p[0]; val.y = p[1]; val.z = p[2]; val.w = p[3];
        *(float4*)&out[(size_t)ii * (2 * N_COL) + (size_t)set * N_COL + colbase + q * 4] = val;
    }
}

extern "C" void kernel_launch(void* const* d_in, const int* in_sizes, int n_in,
                              void* d_out, int out_size, void* d_ws, size_t ws_size,
                              hipStream_t stream) {
    const float* x   = (const float*)d_in[0];
    const float* y   = (const float*)d_in[1];
    const float* pwq = (const float*)d_in[2];
    const float* pwk = (const float*)d_in[3];
    const float* pwv = (const float*)d_in[4];
    const float* pbq = (const float*)d_in[5];
    const float* pbk = (const float*)d_in[6];
    const float* pbv = (const float*)d_in[7];
    const float* pwo = (const float*)d_in[8];
    const float* pbo = (const float*)d_in[9];
    float* out = (float*)d_out;

    rsca_fused<<<dim3(N_COL / CPB), dim3(NT), 0, stream>>>(
        x, y, pwq, pwk, pwv, pbq, pbk, pbv, pwo, pbo, out);
}